// Round 1
// baseline (691.432 us; speedup 1.0000x reference)
//
#include <hip/hip_runtime.h>

#define B 64
#define P 32768
#define G 64

// ---------------- workspace layout (bytes) ----------------
// 0       : double acc[8]      (acc[0]=loss_l, acc[1]=loss_c, acc[2]=loss_landm)
// 256     : int num_pos[64]
// 512     : int any_valid[64]
// 1024    : u64 bp_packed[B*G]          (32768 B)
// 33792   : float truth_pre[B*G*8]      (131072 B)  {x1,y1,x2,y2,area,label,0,0}
// 164864  : float priors_pre[P*8]       (1048576 B) {px1,py1,px2,py2,area,0,0,0}
// 1213440 : float bto[B*P]              (8388608 B)
// 9602048 : int   bti[B*P]              (8388608 B)
// 17990656: float c_neg[B*P]            (8388608 B)
// total ~25.2 MB

__device__ __forceinline__ float sl1(float d) {
    float ad = fabsf(d);
    return (ad < 1.0f) ? 0.5f * d * d : (ad - 0.5f);
}

__global__ void k0_init(const float* __restrict__ priors, const float* __restrict__ targets,
                        float* __restrict__ priors_pre, float* __restrict__ truth_pre,
                        unsigned long long* __restrict__ bp_packed,
                        int* __restrict__ num_pos, int* __restrict__ any_valid,
                        double* __restrict__ acc) {
    int i = blockIdx.x * 256 + threadIdx.x;
    if (i < P) {
        float4 pr = ((const float4*)priors)[i];
        float px1 = pr.x - pr.z * 0.5f, py1 = pr.y - pr.w * 0.5f;
        float px2 = pr.x + pr.z * 0.5f, py2 = pr.y + pr.w * 0.5f;
        float area = (px2 - px1) * (py2 - py1);
        float* o = priors_pre + (size_t)i * 8;
        o[0] = px1; o[1] = py1; o[2] = px2; o[3] = py2; o[4] = area; o[5] = 0.f; o[6] = 0.f; o[7] = 0.f;
    }
    if (i < B * G) {
        const float* t = targets + (size_t)i * 15;
        float x1 = t[0], y1 = t[1], x2 = t[2], y2 = t[3];
        float* o = truth_pre + (size_t)i * 8;
        o[0] = x1; o[1] = y1; o[2] = x2; o[3] = y2;
        o[4] = (x2 - x1) * (y2 - y1); o[5] = t[14]; o[6] = 0.f; o[7] = 0.f;
        bp_packed[i] = 0ull;
    }
    if (i < B) { num_pos[i] = 0; any_valid[i] = 0; }
    if (i < 8) acc[i] = 0.0;
}

__launch_bounds__(256, 4)
__global__ void k1_match(const float* __restrict__ priors_pre, const float* __restrict__ truth_pre,
                         float* __restrict__ bto, int* __restrict__ bti,
                         unsigned long long* __restrict__ bp_packed) {
    __shared__ float ious[32 * 257];
    __shared__ unsigned long long part[256];
    int b = blockIdx.y, tid = threadIdx.x;
    int p = blockIdx.x * 256 + tid;

    const float4 q = *(const float4*)(priors_pre + (size_t)p * 8);
    float pa = priors_pre[(size_t)p * 8 + 4];
    float px1 = q.x, py1 = q.y, px2 = q.z, py2 = q.w;

    float bestv = 0.f;
    int bestg = 0;

    for (int half = 0; half < 2; ++half) {
        for (int j = 0; j < 32; ++j) {
            int g = half * 32 + j;
            const float* t = truth_pre + ((size_t)b * G + g) * 8;   // wave-uniform -> s_load
            float lx = fmaxf(px1, t[0]);
            float ly = fmaxf(py1, t[1]);
            float rx = fminf(px2, t[2]);
            float ry = fminf(py2, t[3]);
            float w = fmaxf(rx - lx, 0.f), h = fmaxf(ry - ly, 0.f);
            float inter = w * h;
            float denom = pa + t[4] - inter;
            float iou = inter * __builtin_amdgcn_rcpf(denom);
            ious[j * 257 + tid] = iou;
            if (iou > bestv) { bestv = iou; bestg = g; }   // strict > : first-g wins ties
        }
        __syncthreads();
        // transpose-reduce: 8 threads per g, interleave so a wave hits 32 distinct banks
        int gr = tid & 31, c = tid >> 5;
        unsigned long long best = 0ull;
        int pbase = blockIdx.x * 256 + c * 32;
        for (int j = 0; j < 32; ++j) {
            float v = ious[gr * 257 + c * 32 + j];
            unsigned long long pk =
                ((unsigned long long)__float_as_uint(v) << 32) | (unsigned int)(~(pbase + j));
            if (pk > best) best = pk;   // ties in value -> larger ~p -> smaller p (first occurrence)
        }
        part[tid] = best;
        __syncthreads();
        if (tid < 32) {
            unsigned long long m = part[tid];
#pragma unroll
            for (int cc = 1; cc < 8; ++cc) {
                unsigned long long o = part[tid + cc * 32];
                if (o > m) m = o;
            }
            atomicMax(&bp_packed[b * G + half * 32 + tid], m);
        }
        __syncthreads();
    }
    bto[(size_t)b * P + p] = bestv;
    bti[(size_t)b * P + p] = bestg;
}

__global__ void k2_force(const unsigned long long* __restrict__ bp_packed,
                         float* __restrict__ bto, int* __restrict__ bti,
                         int* __restrict__ any_valid) {
    int b = blockIdx.x, g = threadIdx.x;   // 64 threads = 1 wave
    unsigned long long pk = bp_packed[b * G + g];
    float bpo = __uint_as_float((unsigned int)(pk >> 32));
    unsigned int bpi = ~((unsigned int)pk);
    bool valid = bpo >= 0.2f;
    unsigned long long ball = __ballot(valid);
    if (g == 0) any_valid[b] = (ball != 0ull) ? 1 : 0;
    if (valid) bto[(size_t)b * P + bpi] = 2.0f;            // .at[].max(2.0): all racers write 2.0
    atomicMax(&bti[(size_t)b * P + bpi], 256 + g);         // .at[].set: last (highest g) wins
}

__launch_bounds__(256, 4)
__global__ void k3_loss(const float* __restrict__ loc_data, const float* __restrict__ conf_data,
                        const float* __restrict__ landm_data, const float* __restrict__ priors,
                        const float* __restrict__ targets,
                        const float* __restrict__ bto, const int* __restrict__ bti,
                        const int* __restrict__ any_valid,
                        float* __restrict__ c_neg, int* __restrict__ num_pos,
                        double* __restrict__ acc) {
    __shared__ float st[G * 15];
    __shared__ float rbuf[12];
    __shared__ int ribuf[4];
    int b = blockIdx.y, tid = threadIdx.x;
    int p = blockIdx.x * 256 + tid;
    for (int i = tid; i < G * 15; i += 256) st[i] = targets[(size_t)b * G * 15 + i];
    __syncthreads();

    size_t idx = (size_t)b * P + p;
    int v = bti[idx];
    int g = (v >= 256) ? (v - 256) : v;
    float ov = bto[idx];
    int conf = 0;
    if (any_valid[b] != 0 && ov >= 0.35f) conf = (int)st[g * 15 + 14];

    const float* cd = conf_data + idx * 3;
    float c0 = cd[0], c1 = cd[1], c2 = cd[2];
    float m = fmaxf(c0, fmaxf(c1, c2));
    float lse = m + __logf(__expf(c0 - m) + __expf(c1 - m) + __expf(c2 - m));
    float gath = (conf == 0) ? c0 : ((conf == 1) ? c1 : c2);
    float lc = lse - gath;

    float cn = 0.f, lloss = 0.f, lmloss = 0.f, plse = 0.f;
    int np = 0;
    if (conf != 0) { np = 1; plse = lc; }
    else cn = fmaxf(lc, 0.f);   // mathematically >=0; clamp keeps radix-select bits monotone
    c_neg[idx] = cn;

    if (conf != 0) {
        float4 pr = ((const float4*)priors)[p];    // cx,cy,w,h
        const float* t = st + g * 15;
        float t0 = t[0], t1 = t[1], t2 = t[2], t3 = t[3];
        float gcx = ((t0 + t2) * 0.5f - pr.x) / (0.1f * pr.z);
        float gcy = ((t1 + t3) * 0.5f - pr.y) / (0.1f * pr.w);
        float gw = __logf((t2 - t0) / pr.z) / 0.2f;
        float gh = __logf((t3 - t1) / pr.w) / 0.2f;
        float4 ld = ((const float4*)loc_data)[idx];
        lloss = sl1(ld.x - gcx) + sl1(ld.y - gcy) + sl1(ld.z - gw) + sl1(ld.w - gh);

        int dims = (conf == 1) ? 10 : 4;
        const float* lmd = landm_data + idx * 10;
        for (int d = 0; d < dims; ++d) {
            float pc = (d & 1) ? pr.y : pr.x;
            float ps = (d & 1) ? pr.w : pr.z;
            float gv = (t[4 + d] - pc) / (0.1f * ps);
            lmloss += sl1(lmd[d] - gv);
        }
    }

    // block reduction: wave shuffle then cross-wave LDS
    for (int off = 32; off > 0; off >>= 1) {
        lloss  += __shfl_down(lloss, off);
        plse   += __shfl_down(plse, off);
        lmloss += __shfl_down(lmloss, off);
        np     += __shfl_down(np, off);
    }
    int wave = tid >> 6, lane = tid & 63;
    if (lane == 0) { rbuf[wave] = lloss; rbuf[4 + wave] = plse; rbuf[8 + wave] = lmloss; ribuf[wave] = np; }
    __syncthreads();
    if (tid == 0) {
        float a = rbuf[0] + rbuf[1] + rbuf[2] + rbuf[3];
        float bb = rbuf[4] + rbuf[5] + rbuf[6] + rbuf[7];
        float cc = rbuf[8] + rbuf[9] + rbuf[10] + rbuf[11];
        int n = ribuf[0] + ribuf[1] + ribuf[2] + ribuf[3];
        if (a != 0.f) atomicAdd(&acc[0], (double)a);
        if (bb != 0.f) atomicAdd(&acc[1], (double)bb);
        if (cc != 0.f) atomicAdd(&acc[2], (double)cc);
        if (n) atomicAdd(&num_pos[b], n);
    }
}

__global__ void k4_mine(const float* __restrict__ c_neg, const int* __restrict__ num_pos,
                        double* __restrict__ acc) {
    __shared__ unsigned int hist[256];
    __shared__ unsigned int sh_prefix, sh_rem;
    __shared__ double sd[4];
    __shared__ unsigned int sc[4];
    int b = blockIdx.x, tid = threadIdx.x;
    int npb = num_pos[b];
    long long k = 7LL * npb;
    if (k > P - 1) k = P - 1;
    if (k <= 0) return;
    const float* cb = c_neg + (size_t)b * P;

    unsigned int prefix = 0, remaining = (unsigned int)k;
    for (int byte = 3; byte >= 0; --byte) {
        hist[tid] = 0;
        __syncthreads();
        int shift = byte * 8;
        unsigned int himask = (byte == 3) ? 0u : (0xFFFFFFFFu << (shift + 8));
        for (int i = tid; i < P; i += 256) {
            unsigned int u = __float_as_uint(cb[i]);
            if ((u & himask) == (prefix & himask))
                atomicAdd(&hist[(u >> shift) & 255u], 1u);
        }
        __syncthreads();
        if (tid == 0) {
            unsigned int c = 0; int sel = 0;
            for (int bin = 255; bin >= 0; --bin) {
                unsigned int nc = c + hist[bin];
                if (nc >= remaining) { sel = bin; break; }
                c = nc;
            }
            remaining -= c;
            prefix |= ((unsigned int)sel) << shift;
            sh_prefix = prefix; sh_rem = remaining;
        }
        __syncthreads();
        prefix = sh_prefix; remaining = sh_rem;
        __syncthreads();
    }
    float t = __uint_as_float(prefix);   // exact k-th largest value (bit pattern)

    double s = 0.0; unsigned int cgt = 0;
    for (int i = tid; i < P; i += 256) {
        float v = cb[i];
        if (v > t) { s += (double)v; cgt++; }
    }
    for (int off = 32; off > 0; off >>= 1) {
        s += __shfl_down(s, off);
        cgt += __shfl_down(cgt, off);
    }
    int wave = tid >> 6, lane = tid & 63;
    if (lane == 0) { sd[wave] = s; sc[wave] = cgt; }
    __syncthreads();
    if (tid == 0) {
        double tot = sd[0] + sd[1] + sd[2] + sd[3];
        unsigned int cg = sc[0] + sc[1] + sc[2] + sc[3];
        tot += (double)(k - (long long)cg) * (double)t;   // tie-fill at threshold
        atomicAdd(&acc[1], tot);
    }
}

__global__ void k5_final(const int* __restrict__ num_pos, const double* __restrict__ acc,
                         float* __restrict__ out) {
    int tid = threadIdx.x;   // 64 threads = 1 wave
    int n = num_pos[tid];
    for (int off = 32; off > 0; off >>= 1) n += __shfl_down(n, off);
    if (tid == 0) {
        double N = (double)(n < 1 ? 1 : n);   // N == N1 here (conf in {0,1,2})
        out[0] = (float)(acc[0] / N);
        out[1] = (float)(acc[1] / N);
        out[2] = (float)(acc[2] / N);
    }
}

extern "C" void kernel_launch(void* const* d_in, const int* in_sizes, int n_in,
                              void* d_out, int out_size, void* d_ws, size_t ws_size,
                              hipStream_t stream) {
    const float* loc     = (const float*)d_in[0];
    const float* confd   = (const float*)d_in[1];
    const float* landm   = (const float*)d_in[2];
    const float* priors  = (const float*)d_in[3];
    const float* targets = (const float*)d_in[4];
    float* out = (float*)d_out;

    char* ws = (char*)d_ws;
    double* acc                  = (double*)(ws + 0);
    int* num_pos                 = (int*)(ws + 256);
    int* any_valid               = (int*)(ws + 512);
    unsigned long long* bp       = (unsigned long long*)(ws + 1024);
    float* truth_pre             = (float*)(ws + 33792);
    float* priors_pre            = (float*)(ws + 164864);
    float* bto                   = (float*)(ws + 1213440);
    int* bti                     = (int*)(ws + 9602048);
    float* c_neg                 = (float*)(ws + 17990656);

    k0_init<<<dim3(P / 256), dim3(256), 0, stream>>>(priors, targets, priors_pre, truth_pre,
                                                     bp, num_pos, any_valid, acc);
    k1_match<<<dim3(P / 256, B), dim3(256), 0, stream>>>(priors_pre, truth_pre, bto, bti, bp);
    k2_force<<<dim3(B), dim3(64), 0, stream>>>(bp, bto, bti, any_valid);
    k3_loss<<<dim3(P / 256, B), dim3(256), 0, stream>>>(loc, confd, landm, priors, targets,
                                                        bto, bti, any_valid, c_neg, num_pos, acc);
    k4_mine<<<dim3(B), dim3(256), 0, stream>>>(c_neg, num_pos, acc);
    k5_final<<<1, 64, 0, stream>>>(num_pos, acc, out);
}

// Round 2
// 472.960 us; speedup vs baseline: 1.4619x; 1.4619x over previous
//
#include <hip/hip_runtime.h>

#define B 64
#define P 32768
#define G 64

// ---------------- workspace layout (bytes) ----------------
// 0       : double acc[8]      (acc[1] = k4's mined-negative conf loss)
// 256     : int num_pos[64]
// 512     : int any_valid[64]
// 1024    : u64 bp_packed[B*G]          (32768 B)
// 33792   : float truth_pre[B*G*8]      (131072 B)  {x1,y1,x2,y2,area,label,0,0}
// 164864  : float4 part3[8192]          (131072 B)  -- aliases priors_pre region head
// 164864  : float priors_pre[P*8]       (1048576 B) {px1,py1,px2,py2,area,0,0,0}
//           (priors_pre dead after k1; part3 written by k3, read by k5 -- safe alias)
// 1213440 : float bto[B*P]              (8388608 B)
// 9602048 : int   bti[B*P]              (8388608 B)
// 17990656: float c_neg[B*P]            (8388608 B)

__device__ __forceinline__ float sl1(float d) {
    float ad = fabsf(d);
    return (ad < 1.0f) ? 0.5f * d * d : (ad - 0.5f);
}

__global__ void k0_init(const float* __restrict__ priors, const float* __restrict__ targets,
                        float* __restrict__ priors_pre, float* __restrict__ truth_pre,
                        unsigned long long* __restrict__ bp_packed,
                        int* __restrict__ num_pos, int* __restrict__ any_valid,
                        double* __restrict__ acc) {
    int i = blockIdx.x * 256 + threadIdx.x;
    if (i < P) {
        float4 pr = ((const float4*)priors)[i];
        float px1 = pr.x - pr.z * 0.5f, py1 = pr.y - pr.w * 0.5f;
        float px2 = pr.x + pr.z * 0.5f, py2 = pr.y + pr.w * 0.5f;
        float area = (px2 - px1) * (py2 - py1);
        float* o = priors_pre + (size_t)i * 8;
        o[0] = px1; o[1] = py1; o[2] = px2; o[3] = py2; o[4] = area; o[5] = 0.f; o[6] = 0.f; o[7] = 0.f;
    }
    if (i < B * G) {
        const float* t = targets + (size_t)i * 15;
        float x1 = t[0], y1 = t[1], x2 = t[2], y2 = t[3];
        float* o = truth_pre + (size_t)i * 8;
        o[0] = x1; o[1] = y1; o[2] = x2; o[3] = y2;
        o[4] = (x2 - x1) * (y2 - y1); o[5] = t[14]; o[6] = 0.f; o[7] = 0.f;
        bp_packed[i] = 0ull;
    }
    if (i < B) { num_pos[i] = 0; any_valid[i] = 0; }
    if (i < 8) acc[i] = 0.0;
}

__launch_bounds__(256, 4)
__global__ void k1_match(const float* __restrict__ priors_pre, const float* __restrict__ truth_pre,
                         float* __restrict__ bto, int* __restrict__ bti,
                         unsigned long long* __restrict__ bp_packed) {
    __shared__ float ious[32 * 257];
    __shared__ unsigned long long part[256];
    int b = blockIdx.y, tid = threadIdx.x;
    int p = blockIdx.x * 256 + tid;

    const float4 q = *(const float4*)(priors_pre + (size_t)p * 8);
    float pa = priors_pre[(size_t)p * 8 + 4];
    float px1 = q.x, py1 = q.y, px2 = q.z, py2 = q.w;

    float bestv = 0.f;
    int bestg = 0;

    for (int half = 0; half < 2; ++half) {
        for (int j = 0; j < 32; ++j) {
            int g = half * 32 + j;
            const float* t = truth_pre + ((size_t)b * G + g) * 8;   // wave-uniform -> s_load
            float lx = fmaxf(px1, t[0]);
            float ly = fmaxf(py1, t[1]);
            float rx = fminf(px2, t[2]);
            float ry = fminf(py2, t[3]);
            float w = fmaxf(rx - lx, 0.f), h = fmaxf(ry - ly, 0.f);
            float inter = w * h;
            float denom = pa + t[4] - inter;
            float iou = inter * __builtin_amdgcn_rcpf(denom);
            ious[j * 257 + tid] = iou;
            if (iou > bestv) { bestv = iou; bestg = g; }   // strict > : first-g wins ties
        }
        __syncthreads();
        // transpose-reduce: 8 threads per g, interleave so a wave hits 32 distinct banks
        int gr = tid & 31, c = tid >> 5;
        unsigned long long best = 0ull;
        int pbase = blockIdx.x * 256 + c * 32;
        for (int j = 0; j < 32; ++j) {
            float v = ious[gr * 257 + c * 32 + j];
            unsigned long long pk =
                ((unsigned long long)__float_as_uint(v) << 32) | (unsigned int)(~(pbase + j));
            if (pk > best) best = pk;   // ties in value -> larger ~p -> smaller p (first occurrence)
        }
        part[tid] = best;
        __syncthreads();
        if (tid < 32) {
            unsigned long long m = part[tid];
#pragma unroll
            for (int cc = 1; cc < 8; ++cc) {
                unsigned long long o = part[tid + cc * 32];
                if (o > m) m = o;
            }
            atomicMax(&bp_packed[b * G + half * 32 + tid], m);
        }
        __syncthreads();
    }
    bto[(size_t)b * P + p] = bestv;
    bti[(size_t)b * P + p] = bestg;
}

__global__ void k2_force(const unsigned long long* __restrict__ bp_packed,
                         float* __restrict__ bto, int* __restrict__ bti,
                         int* __restrict__ any_valid) {
    int b = blockIdx.x, g = threadIdx.x;   // 64 threads = 1 wave
    unsigned long long pk = bp_packed[b * G + g];
    float bpo = __uint_as_float((unsigned int)(pk >> 32));
    unsigned int bpi = ~((unsigned int)pk);
    bool valid = bpo >= 0.2f;
    unsigned long long ball = __ballot(valid);
    if (g == 0) any_valid[b] = (ball != 0ull) ? 1 : 0;
    if (valid) bto[(size_t)b * P + bpi] = 2.0f;            // .at[].max(2.0): all racers write 2.0
    atomicMax(&bti[(size_t)b * P + bpi], 256 + g);         // .at[].set: last (highest g) wins
}

__launch_bounds__(256, 4)
__global__ void k3_loss(const float* __restrict__ loc_data, const float* __restrict__ conf_data,
                        const float* __restrict__ landm_data, const float* __restrict__ priors,
                        const float* __restrict__ targets,
                        const float* __restrict__ bto, const int* __restrict__ bti,
                        const int* __restrict__ any_valid,
                        float* __restrict__ c_neg, int* __restrict__ num_pos,
                        float4* __restrict__ part3) {
    __shared__ float st[G * 15];
    __shared__ float rbuf[12];
    __shared__ int ribuf[4];
    int b = blockIdx.y, tid = threadIdx.x;
    int p = blockIdx.x * 256 + tid;
    for (int i = tid; i < G * 15; i += 256) st[i] = targets[(size_t)b * G * 15 + i];
    __syncthreads();

    size_t idx = (size_t)b * P + p;
    int v = bti[idx];
    int g = (v >= 256) ? (v - 256) : v;
    float ov = bto[idx];
    int conf = 0;
    if (any_valid[b] != 0 && ov >= 0.35f) conf = (int)st[g * 15 + 14];

    const float* cd = conf_data + idx * 3;
    float c0 = cd[0], c1 = cd[1], c2 = cd[2];
    float m = fmaxf(c0, fmaxf(c1, c2));
    float lse = m + __logf(__expf(c0 - m) + __expf(c1 - m) + __expf(c2 - m));
    float gath = (conf == 0) ? c0 : ((conf == 1) ? c1 : c2);
    float lc = lse - gath;

    float cn = 0.f, lloss = 0.f, lmloss = 0.f, plse = 0.f;
    int np = 0;
    if (conf != 0) { np = 1; plse = lc; }
    else cn = fmaxf(lc, 0.f);   // mathematically >=0; clamp keeps radix-select bits monotone
    c_neg[idx] = cn;

    if (conf != 0) {
        float4 pr = ((const float4*)priors)[p];    // cx,cy,w,h
        const float* t = st + g * 15;
        float t0 = t[0], t1 = t[1], t2 = t[2], t3 = t[3];
        float gcx = ((t0 + t2) * 0.5f - pr.x) / (0.1f * pr.z);
        float gcy = ((t1 + t3) * 0.5f - pr.y) / (0.1f * pr.w);
        float gw = __logf((t2 - t0) / pr.z) / 0.2f;
        float gh = __logf((t3 - t1) / pr.w) / 0.2f;
        float4 ld = ((const float4*)loc_data)[idx];
        lloss = sl1(ld.x - gcx) + sl1(ld.y - gcy) + sl1(ld.z - gw) + sl1(ld.w - gh);

        int dims = (conf == 1) ? 10 : 4;
        const float* lmd = landm_data + idx * 10;
        for (int d = 0; d < dims; ++d) {
            float pc = (d & 1) ? pr.y : pr.x;
            float ps = (d & 1) ? pr.w : pr.z;
            float gv = (t[4 + d] - pc) / (0.1f * ps);
            lmloss += sl1(lmd[d] - gv);
        }
    }

    // block reduction: wave shuffle then cross-wave LDS
    for (int off = 32; off > 0; off >>= 1) {
        lloss  += __shfl_down(lloss, off);
        plse   += __shfl_down(plse, off);
        lmloss += __shfl_down(lmloss, off);
        np     += __shfl_down(np, off);
    }
    int wave = tid >> 6, lane = tid & 63;
    if (lane == 0) { rbuf[wave] = lloss; rbuf[4 + wave] = plse; rbuf[8 + wave] = lmloss; ribuf[wave] = np; }
    __syncthreads();
    if (tid == 0) {
        float a = rbuf[0] + rbuf[1] + rbuf[2] + rbuf[3];
        float bb = rbuf[4] + rbuf[5] + rbuf[6] + rbuf[7];
        float cc = rbuf[8] + rbuf[9] + rbuf[10] + rbuf[11];
        int n = ribuf[0] + ribuf[1] + ribuf[2] + ribuf[3];
        // one uncontended float4 store per block instead of 3 contended f64 atomics
        part3[b * gridDim.x + blockIdx.x] = make_float4(a, bb, cc, (float)n);
        if (n) atomicAdd(&num_pos[b], n);   // 64 addresses, needed by k4 before k5
    }
}

__global__ void k4_mine(const float* __restrict__ c_neg, const int* __restrict__ num_pos,
                        double* __restrict__ acc) {
    __shared__ unsigned int hist[256];
    __shared__ unsigned int sh_prefix, sh_rem;
    __shared__ double sd[4];
    __shared__ unsigned int sc[4];
    int b = blockIdx.x, tid = threadIdx.x;
    int npb = num_pos[b];
    long long k = 7LL * npb;
    if (k > P - 1) k = P - 1;
    if (k <= 0) return;
    const float* cb = c_neg + (size_t)b * P;

    unsigned int prefix = 0, remaining = (unsigned int)k;
    for (int byte = 3; byte >= 0; --byte) {
        hist[tid] = 0;
        __syncthreads();
        int shift = byte * 8;
        unsigned int himask = (byte == 3) ? 0u : (0xFFFFFFFFu << (shift + 8));
        for (int i = tid; i < P; i += 256) {
            unsigned int u = __float_as_uint(cb[i]);
            if ((u & himask) == (prefix & himask))
                atomicAdd(&hist[(u >> shift) & 255u], 1u);
        }
        __syncthreads();
        if (tid == 0) {
            unsigned int c = 0; int sel = 0;
            for (int bin = 255; bin >= 0; --bin) {
                unsigned int nc = c + hist[bin];
                if (nc >= remaining) { sel = bin; break; }
                c = nc;
            }
            remaining -= c;
            prefix |= ((unsigned int)sel) << shift;
            sh_prefix = prefix; sh_rem = remaining;
        }
        __syncthreads();
        prefix = sh_prefix; remaining = sh_rem;
        __syncthreads();
    }
    float t = __uint_as_float(prefix);   // exact k-th largest value (bit pattern)

    double s = 0.0; unsigned int cgt = 0;
    for (int i = tid; i < P; i += 256) {
        float v = cb[i];
        if (v > t) { s += (double)v; cgt++; }
    }
    for (int off = 32; off > 0; off >>= 1) {
        s += __shfl_down(s, off);
        cgt += __shfl_down(cgt, off);
    }
    int wave = tid >> 6, lane = tid & 63;
    if (lane == 0) { sd[wave] = s; sc[wave] = cgt; }
    __syncthreads();
    if (tid == 0) {
        double tot = sd[0] + sd[1] + sd[2] + sd[3];
        unsigned int cg = sc[0] + sc[1] + sc[2] + sc[3];
        tot += (double)(k - (long long)cg) * (double)t;   // tie-fill at threshold
        atomicAdd(&acc[1], tot);   // only 64 blocks -> negligible contention
    }
}

__global__ void k5_final(const float4* __restrict__ part3, const int* __restrict__ num_pos,
                         const double* __restrict__ acc, float* __restrict__ out,
                         int nparts) {
    __shared__ double sb[3][4];
    int tid = threadIdx.x;
    double sl = 0.0, scn = 0.0, sm = 0.0;
    for (int i = tid; i < nparts; i += 256) {
        float4 v = part3[i];
        sl += (double)v.x; scn += (double)v.y; sm += (double)v.z;
    }
    for (int off = 32; off > 0; off >>= 1) {
        sl += __shfl_down(sl, off);
        scn += __shfl_down(scn, off);
        sm += __shfl_down(sm, off);
    }
    int wave = tid >> 6, lane = tid & 63;
    if (lane == 0) { sb[0][wave] = sl; sb[1][wave] = scn; sb[2][wave] = sm; }
    __syncthreads();
    if (tid == 0) {
        double L = sb[0][0] + sb[0][1] + sb[0][2] + sb[0][3];
        double C = sb[1][0] + sb[1][1] + sb[1][2] + sb[1][3] + acc[1];
        double M = sb[2][0] + sb[2][1] + sb[2][2] + sb[2][3];
        int n = 0;
        for (int i = 0; i < B; ++i) n += num_pos[i];
        double N = (double)(n < 1 ? 1 : n);   // N == N1 here (labels in {1,2})
        out[0] = (float)(L / N);
        out[1] = (float)(C / N);
        out[2] = (float)(M / N);
    }
}

extern "C" void kernel_launch(void* const* d_in, const int* in_sizes, int n_in,
                              void* d_out, int out_size, void* d_ws, size_t ws_size,
                              hipStream_t stream) {
    const float* loc     = (const float*)d_in[0];
    const float* confd   = (const float*)d_in[1];
    const float* landm   = (const float*)d_in[2];
    const float* priors  = (const float*)d_in[3];
    const float* targets = (const float*)d_in[4];
    float* out = (float*)d_out;

    char* ws = (char*)d_ws;
    double* acc                  = (double*)(ws + 0);
    int* num_pos                 = (int*)(ws + 256);
    int* any_valid               = (int*)(ws + 512);
    unsigned long long* bp       = (unsigned long long*)(ws + 1024);
    float* truth_pre             = (float*)(ws + 33792);
    float* priors_pre            = (float*)(ws + 164864);
    float4* part3                = (float4*)(ws + 164864);  // aliases priors_pre (dead after k1)
    float* bto                   = (float*)(ws + 1213440);
    int* bti                     = (int*)(ws + 9602048);
    float* c_neg                 = (float*)(ws + 17990656);

    k0_init<<<dim3(P / 256), dim3(256), 0, stream>>>(priors, targets, priors_pre, truth_pre,
                                                     bp, num_pos, any_valid, acc);
    k1_match<<<dim3(P / 256, B), dim3(256), 0, stream>>>(priors_pre, truth_pre, bto, bti, bp);
    k2_force<<<dim3(B), dim3(64), 0, stream>>>(bp, bto, bti, any_valid);
    k3_loss<<<dim3(P / 256, B), dim3(256), 0, stream>>>(loc, confd, landm, priors, targets,
                                                        bto, bti, any_valid, c_neg, num_pos, part3);
    k4_mine<<<dim3(B), dim3(256), 0, stream>>>(c_neg, num_pos, acc);
    k5_final<<<1, 256, 0, stream>>>(part3, num_pos, acc, out, (P / 256) * B);
}

// Round 3
// 364.574 us; speedup vs baseline: 1.8965x; 1.2973x over previous
//
#include <hip/hip_runtime.h>

#define B 64
#define P 32768
#define G 64

// ---------------- workspace layout (bytes) ----------------
// 0       : double acc[8]      (acc[1] = k4's mined-negative conf loss)
// 256     : int num_pos[64]
// 512     : int any_valid[64]
// 1024    : u64 bp_packed[B*G]          (32768 B)
// 33792   : float truth_pre[B*G*8]      (131072 B)  {x1,y1,x2,y2,area,label,0,0}
// 164864  : float4 part3[8192]          (131072 B)  -- aliases priors_pre region head
// 164864  : float priors_pre[P*8]       (1048576 B) {px1,py1,px2,py2,area,0,0,0}
//           (priors_pre dead after k1; part3 written by k3, read by k5 -- safe alias)
// 1213440 : float bto[B*P]              (8388608 B)
// 9602048 : int   bti[B*P]              (8388608 B)
// 17990656: float c_neg[B*P]            (8388608 B)

__device__ __forceinline__ float sl1(float d) {
    float ad = fabsf(d);
    return (ad < 1.0f) ? 0.5f * d * d : (ad - 0.5f);
}

__global__ void k0_init(const float* __restrict__ priors, const float* __restrict__ targets,
                        float* __restrict__ priors_pre, float* __restrict__ truth_pre,
                        unsigned long long* __restrict__ bp_packed,
                        int* __restrict__ num_pos, int* __restrict__ any_valid,
                        double* __restrict__ acc) {
    int i = blockIdx.x * 256 + threadIdx.x;
    if (i < P) {
        float4 pr = ((const float4*)priors)[i];
        float px1 = pr.x - pr.z * 0.5f, py1 = pr.y - pr.w * 0.5f;
        float px2 = pr.x + pr.z * 0.5f, py2 = pr.y + pr.w * 0.5f;
        float area = (px2 - px1) * (py2 - py1);
        float* o = priors_pre + (size_t)i * 8;
        o[0] = px1; o[1] = py1; o[2] = px2; o[3] = py2; o[4] = area; o[5] = 0.f; o[6] = 0.f; o[7] = 0.f;
    }
    if (i < B * G) {
        const float* t = targets + (size_t)i * 15;
        float x1 = t[0], y1 = t[1], x2 = t[2], y2 = t[3];
        float* o = truth_pre + (size_t)i * 8;
        o[0] = x1; o[1] = y1; o[2] = x2; o[3] = y2;
        o[4] = (x2 - x1) * (y2 - y1); o[5] = t[14]; o[6] = 0.f; o[7] = 0.f;
        bp_packed[i] = 0ull;
    }
    if (i < B) { num_pos[i] = 0; any_valid[i] = 0; }
    if (i < 8) acc[i] = 0.0;
}

__launch_bounds__(256, 4)
__global__ void k1_match(const float* __restrict__ priors_pre, const float* __restrict__ truth_pre,
                         float* __restrict__ bto, int* __restrict__ bti,
                         unsigned long long* __restrict__ bp_packed) {
    __shared__ float ious[32 * 257];
    __shared__ unsigned long long part[256];
    int b = blockIdx.y, tid = threadIdx.x;
    int p = blockIdx.x * 256 + tid;

    const float4 q = *(const float4*)(priors_pre + (size_t)p * 8);
    float pa = priors_pre[(size_t)p * 8 + 4];
    float px1 = q.x, py1 = q.y, px2 = q.z, py2 = q.w;

    float bestv = 0.f;
    int bestg = 0;

    for (int half = 0; half < 2; ++half) {
        for (int j = 0; j < 32; ++j) {
            int g = half * 32 + j;
            const float* t = truth_pre + ((size_t)b * G + g) * 8;   // wave-uniform -> s_load
            float lx = fmaxf(px1, t[0]);
            float ly = fmaxf(py1, t[1]);
            float rx = fminf(px2, t[2]);
            float ry = fminf(py2, t[3]);
            float w = fmaxf(rx - lx, 0.f), h = fmaxf(ry - ly, 0.f);
            float inter = w * h;
            float denom = pa + t[4] - inter;
            float iou = inter * __builtin_amdgcn_rcpf(denom);
            ious[j * 257 + tid] = iou;
            if (iou > bestv) { bestv = iou; bestg = g; }   // strict > : first-g wins ties
        }
        __syncthreads();
        // transpose-reduce: 8 threads per g, interleave so a wave hits 32 distinct banks
        int gr = tid & 31, c = tid >> 5;
        unsigned long long best = 0ull;
        int pbase = blockIdx.x * 256 + c * 32;
        for (int j = 0; j < 32; ++j) {
            float v = ious[gr * 257 + c * 32 + j];
            unsigned long long pk =
                ((unsigned long long)__float_as_uint(v) << 32) | (unsigned int)(~(pbase + j));
            if (pk > best) best = pk;   // ties in value -> larger ~p -> smaller p (first occurrence)
        }
        part[tid] = best;
        __syncthreads();
        if (tid < 32) {
            unsigned long long m = part[tid];
#pragma unroll
            for (int cc = 1; cc < 8; ++cc) {
                unsigned long long o = part[tid + cc * 32];
                if (o > m) m = o;
            }
            atomicMax(&bp_packed[b * G + half * 32 + tid], m);
        }
        __syncthreads();
    }
    bto[(size_t)b * P + p] = bestv;
    bti[(size_t)b * P + p] = bestg;
}

__global__ void k2_force(const unsigned long long* __restrict__ bp_packed,
                         float* __restrict__ bto, int* __restrict__ bti,
                         int* __restrict__ any_valid) {
    int b = blockIdx.x, g = threadIdx.x;   // 64 threads = 1 wave
    unsigned long long pk = bp_packed[b * G + g];
    float bpo = __uint_as_float((unsigned int)(pk >> 32));
    unsigned int bpi = ~((unsigned int)pk);
    bool valid = bpo >= 0.2f;
    unsigned long long ball = __ballot(valid);
    if (g == 0) any_valid[b] = (ball != 0ull) ? 1 : 0;
    if (valid) bto[(size_t)b * P + bpi] = 2.0f;            // .at[].max(2.0): all racers write 2.0
    atomicMax(&bti[(size_t)b * P + bpi], 256 + g);         // .at[].set: last (highest g) wins
}

__launch_bounds__(256, 4)
__global__ void k3_loss(const float* __restrict__ loc_data, const float* __restrict__ conf_data,
                        const float* __restrict__ landm_data, const float* __restrict__ priors,
                        const float* __restrict__ targets,
                        const float* __restrict__ bto, const int* __restrict__ bti,
                        const int* __restrict__ any_valid,
                        float* __restrict__ c_neg, int* __restrict__ num_pos,
                        float4* __restrict__ part3) {
    __shared__ float st[G * 15];
    __shared__ float rbuf[12];
    __shared__ int ribuf[4];
    int b = blockIdx.y, tid = threadIdx.x;
    int p = blockIdx.x * 256 + tid;
    for (int i = tid; i < G * 15; i += 256) st[i] = targets[(size_t)b * G * 15 + i];
    __syncthreads();

    size_t idx = (size_t)b * P + p;
    int v = bti[idx];
    int g = (v >= 256) ? (v - 256) : v;
    float ov = bto[idx];
    int conf = 0;
    if (any_valid[b] != 0 && ov >= 0.35f) conf = (int)st[g * 15 + 14];

    const float* cd = conf_data + idx * 3;
    float c0 = cd[0], c1 = cd[1], c2 = cd[2];
    float m = fmaxf(c0, fmaxf(c1, c2));
    float lse = m + __logf(__expf(c0 - m) + __expf(c1 - m) + __expf(c2 - m));
    float gath = (conf == 0) ? c0 : ((conf == 1) ? c1 : c2);
    float lc = lse - gath;

    float cn = 0.f, lloss = 0.f, lmloss = 0.f, plse = 0.f;
    int np = 0;
    if (conf != 0) { np = 1; plse = lc; }
    else cn = fmaxf(lc, 0.f);   // mathematically >=0; clamp keeps radix-select bits monotone
    c_neg[idx] = cn;

    if (conf != 0) {
        float4 pr = ((const float4*)priors)[p];    // cx,cy,w,h
        const float* t = st + g * 15;
        float t0 = t[0], t1 = t[1], t2 = t[2], t3 = t[3];
        float gcx = ((t0 + t2) * 0.5f - pr.x) / (0.1f * pr.z);
        float gcy = ((t1 + t3) * 0.5f - pr.y) / (0.1f * pr.w);
        float gw = __logf((t2 - t0) / pr.z) / 0.2f;
        float gh = __logf((t3 - t1) / pr.w) / 0.2f;
        float4 ld = ((const float4*)loc_data)[idx];
        lloss = sl1(ld.x - gcx) + sl1(ld.y - gcy) + sl1(ld.z - gw) + sl1(ld.w - gh);

        int dims = (conf == 1) ? 10 : 4;
        const float* lmd = landm_data + idx * 10;
        for (int d = 0; d < dims; ++d) {
            float pc = (d & 1) ? pr.y : pr.x;
            float ps = (d & 1) ? pr.w : pr.z;
            float gv = (t[4 + d] - pc) / (0.1f * ps);
            lmloss += sl1(lmd[d] - gv);
        }
    }

    // block reduction: wave shuffle then cross-wave LDS
    for (int off = 32; off > 0; off >>= 1) {
        lloss  += __shfl_down(lloss, off);
        plse   += __shfl_down(plse, off);
        lmloss += __shfl_down(lmloss, off);
        np     += __shfl_down(np, off);
    }
    int wave = tid >> 6, lane = tid & 63;
    if (lane == 0) { rbuf[wave] = lloss; rbuf[4 + wave] = plse; rbuf[8 + wave] = lmloss; ribuf[wave] = np; }
    __syncthreads();
    if (tid == 0) {
        float a = rbuf[0] + rbuf[1] + rbuf[2] + rbuf[3];
        float bb = rbuf[4] + rbuf[5] + rbuf[6] + rbuf[7];
        float cc = rbuf[8] + rbuf[9] + rbuf[10] + rbuf[11];
        int n = ribuf[0] + ribuf[1] + ribuf[2] + ribuf[3];
        part3[b * gridDim.x + blockIdx.x] = make_float4(a, bb, cc, (float)n);
        if (n) atomicAdd(&num_pos[b], n);
    }
}

__launch_bounds__(1024, 1)
__global__ void k4_mine(const float* __restrict__ c_neg, const int* __restrict__ num_pos,
                        double* __restrict__ acc) {
    __shared__ unsigned int hist[16][256];   // per-wave replicated histograms
    __shared__ unsigned int chist[256];
    __shared__ unsigned int sh_prefix, sh_rem;
    __shared__ double sd[16];
    __shared__ unsigned int sc[16];
    int b = blockIdx.x, tid = threadIdx.x;
    int wv = tid >> 6, lane = tid & 63;
    int npb = num_pos[b];
    long long k = 7LL * npb;
    if (k > P - 1) k = P - 1;
    if (k <= 0) return;
    const float* cb = c_neg + (size_t)b * P;

    unsigned int prefix = 0, remaining = (unsigned int)k;
    for (int byte = 3; byte >= 0; --byte) {
        for (int i = tid; i < 16 * 256; i += 1024) ((unsigned int*)hist)[i] = 0;
        __syncthreads();
        int shift = byte * 8;
        if (byte == 3) {
            // top byte: values cluster in ~4 exponent bins -> wave leader-loop aggregation
            for (int i = tid; i < P; i += 1024) {
                unsigned int u = __float_as_uint(cb[i]);
                unsigned int bin = u >> 24;
                unsigned long long todo = __ballot(true);
                while (todo) {
                    int src = (int)(__ffsll((unsigned long long)todo) - 1);
                    unsigned int lbin = (unsigned int)__shfl((int)bin, src);
                    unsigned long long mm = __ballot(bin == lbin);
                    if (lane == src) atomicAdd(&hist[wv][lbin], (unsigned int)__popcll(mm));
                    todo &= ~mm;
                }
            }
        } else {
            // lower digits: mantissa bits are spread -> direct per-wave atomics
            unsigned int himask = 0xFFFFFFFFu << (shift + 8);
            for (int i = tid; i < P; i += 1024) {
                unsigned int u = __float_as_uint(cb[i]);
                if ((u & himask) == (prefix & himask))
                    atomicAdd(&hist[wv][(u >> shift) & 255u], 1u);
            }
        }
        __syncthreads();
        if (tid < 256) {
            unsigned int s = 0;
#pragma unroll
            for (int w = 0; w < 16; ++w) s += hist[w][tid];
            chist[tid] = s;
        }
        __syncthreads();
        // parallel bin selection on wave 0: descending suffix scan over 256 bins
        if (wv == 0) {
            int b0 = 255 - 4 * lane;                       // lane 0 owns top chunk
            unsigned int c0 = chist[b0], c1 = chist[b0 - 1], c2 = chist[b0 - 2], c3 = chist[b0 - 3];
            unsigned int csum = c0 + c1 + c2 + c3;
            unsigned int scan = csum;
            for (int off = 1; off < 64; off <<= 1) {
                unsigned int o = (unsigned int)__shfl_up((int)scan, off);
                if (lane >= off) scan += o;
            }
            unsigned int excl = scan - csum;
            if (scan >= remaining && excl < remaining) {   // exactly one lane crosses
                int selbin; unsigned int below;
                if (excl + c0 >= remaining)                 { selbin = b0;     below = excl; }
                else if (excl + c0 + c1 >= remaining)       { selbin = b0 - 1; below = excl + c0; }
                else if (excl + c0 + c1 + c2 >= remaining)  { selbin = b0 - 2; below = excl + c0 + c1; }
                else                                        { selbin = b0 - 3; below = excl + c0 + c1 + c2; }
                sh_prefix = prefix | ((unsigned int)selbin << shift);
                sh_rem = remaining - below;
            }
        }
        __syncthreads();
        prefix = sh_prefix; remaining = sh_rem;
        __syncthreads();
    }
    float t = __uint_as_float(prefix);   // exact k-th largest value (bit pattern)

    double s = 0.0; unsigned int cgt = 0;
    for (int i = tid; i < P; i += 1024) {
        float v = cb[i];
        if (v > t) { s += (double)v; cgt++; }
    }
    for (int off = 32; off > 0; off >>= 1) {
        s += __shfl_down(s, off);
        cgt += __shfl_down(cgt, off);
    }
    if (lane == 0) { sd[wv] = s; sc[wv] = cgt; }
    __syncthreads();
    if (tid == 0) {
        double tot = 0.0; unsigned int cg = 0;
#pragma unroll
        for (int w = 0; w < 16; ++w) { tot += sd[w]; cg += sc[w]; }
        tot += (double)(k - (long long)cg) * (double)t;   // tie-fill at threshold
        atomicAdd(&acc[1], tot);   // 64 blocks -> negligible contention
    }
}

__global__ void k5_final(const float4* __restrict__ part3, const int* __restrict__ num_pos,
                         const double* __restrict__ acc, float* __restrict__ out,
                         int nparts) {
    __shared__ double sb[3][4];
    int tid = threadIdx.x;
    double sl = 0.0, scn = 0.0, sm = 0.0;
    for (int i = tid; i < nparts; i += 256) {
        float4 v = part3[i];
        sl += (double)v.x; scn += (double)v.y; sm += (double)v.z;
    }
    for (int off = 32; off > 0; off >>= 1) {
        sl += __shfl_down(sl, off);
        scn += __shfl_down(scn, off);
        sm += __shfl_down(sm, off);
    }
    int wave = tid >> 6, lane = tid & 63;
    if (lane == 0) { sb[0][wave] = sl; sb[1][wave] = scn; sb[2][wave] = sm; }
    __syncthreads();
    if (tid == 0) {
        double L = sb[0][0] + sb[0][1] + sb[0][2] + sb[0][3];
        double C = sb[1][0] + sb[1][1] + sb[1][2] + sb[1][3] + acc[1];
        double M = sb[2][0] + sb[2][1] + sb[2][2] + sb[2][3];
        int n = 0;
        for (int i = 0; i < B; ++i) n += num_pos[i];
        double N = (double)(n < 1 ? 1 : n);   // N == N1 here (labels in {1,2})
        out[0] = (float)(L / N);
        out[1] = (float)(C / N);
        out[2] = (float)(M / N);
    }
}

extern "C" void kernel_launch(void* const* d_in, const int* in_sizes, int n_in,
                              void* d_out, int out_size, void* d_ws, size_t ws_size,
                              hipStream_t stream) {
    const float* loc     = (const float*)d_in[0];
    const float* confd   = (const float*)d_in[1];
    const float* landm   = (const float*)d_in[2];
    const float* priors  = (const float*)d_in[3];
    const float* targets = (const float*)d_in[4];
    float* out = (float*)d_out;

    char* ws = (char*)d_ws;
    double* acc                  = (double*)(ws + 0);
    int* num_pos                 = (int*)(ws + 256);
    int* any_valid               = (int*)(ws + 512);
    unsigned long long* bp       = (unsigned long long*)(ws + 1024);
    float* truth_pre             = (float*)(ws + 33792);
    float* priors_pre            = (float*)(ws + 164864);
    float4* part3                = (float4*)(ws + 164864);  // aliases priors_pre (dead after k1)
    float* bto                   = (float*)(ws + 1213440);
    int* bti                     = (int*)(ws + 9602048);
    float* c_neg                 = (float*)(ws + 17990656);

    k0_init<<<dim3(P / 256), dim3(256), 0, stream>>>(priors, targets, priors_pre, truth_pre,
                                                     bp, num_pos, any_valid, acc);
    k1_match<<<dim3(P / 256, B), dim3(256), 0, stream>>>(priors_pre, truth_pre, bto, bti, bp);
    k2_force<<<dim3(B), dim3(64), 0, stream>>>(bp, bto, bti, any_valid);
    k3_loss<<<dim3(P / 256, B), dim3(256), 0, stream>>>(loc, confd, landm, priors, targets,
                                                        bto, bti, any_valid, c_neg, num_pos, part3);
    k4_mine<<<dim3(B), dim3(1024), 0, stream>>>(c_neg, num_pos, acc);
    k5_final<<<1, 256, 0, stream>>>(part3, num_pos, acc, out, (P / 256) * B);
}